// Round 5
// baseline (34.641 us; speedup 1.0000x reference)
//
#include <hip/hip_runtime.h>
#include <math.h>

#define LDIM 64
#define QT2 32   // queries per logits tile
#define QW 8     // queries per wave in logits kernel
#define QT3 4    // queries per pv block
#define LOG2E 1.4426950408889634f

static __device__ __forceinline__ float fast_exp2(float x) {
#if __has_builtin(__builtin_amdgcn_exp2f)
    return __builtin_amdgcn_exp2f(x);
#else
    return exp2f(x);
#endif
}

// K1: precompute.
//   Bi[c][g][o] = float4{ B[4g+j][o] },  B[l][o] = b1[l] + pos_obs[o]·(W1[3:6,l]-W1[6:9,l])
//   V[o][l]     = bv[l] + h_obs[o]·Wv[:,l]
//   A[q][l]     = pos_query[q]·(W1[0:3,l]+W1[6:9,l])
//   P4[o]       = (x,y,z, mask ? batch+1 : 0)
//   w2s[l]      = W2[l]*log2e
//   qrange[q]   = [start,end) of q's batch in obs_batch (sorted)
__global__ __launch_bounds__(256) void gano_pre(
    const float* __restrict__ h_obs, const float* __restrict__ pos_obs,
    const float* __restrict__ pos_query,
    const float* __restrict__ W1, const float* __restrict__ b1,
    const float* __restrict__ W2,
    const float* __restrict__ Wv, const float* __restrict__ bv,
    const int* __restrict__ obs_mask, const int* __restrict__ obs_batch,
    const int* __restrict__ query_batch,
    float4* __restrict__ Bi, float4* __restrict__ P4,
    float* __restrict__ V, float* __restrict__ A, float* __restrict__ w2s,
    int2* __restrict__ qrange,
    int No, int NoA, int Nq)
{
    const int gid = blockIdx.x * blockDim.x + threadIdx.x;
    if (gid >= NoA * LDIM) return;
    // V[o][l]
    {
        const int o = gid >> 6, l = gid & 63;
        float vv = 0.0f;
        if (o < No) {
            vv = bv[l];
            #pragma unroll 8
            for (int k = 0; k < LDIM; ++k)
                vv = fmaf(h_obs[o * LDIM + k], Wv[k * LDIM + l], vv);
        }
        V[gid] = vv;
    }
    // Bi[c][g][o]
    if (gid < NoA * 16) {
        const int o = gid & 63, g = (gid >> 6) & 15, c = gid >> 10;
        const int oo = (c << 6) + o;
        float4 r = make_float4(0.f, 0.f, 0.f, 0.f);
        if (oo < No) {
            const float px = pos_obs[oo*3+0], py = pos_obs[oo*3+1], pz = pos_obs[oo*3+2];
            float* rr = (float*)&r;
            #pragma unroll
            for (int j = 0; j < 4; ++j) {
                const int l = 4 * g + j;
                float bb = b1[l];
                bb = fmaf(px, W1[3*LDIM+l] - W1[6*LDIM+l], bb);
                bb = fmaf(py, W1[4*LDIM+l] - W1[7*LDIM+l], bb);
                bb = fmaf(pz, W1[5*LDIM+l] - W1[8*LDIM+l], bb);
                rr[j] = bb;
            }
        }
        Bi[gid] = r;
    }
    // A[q][l]
    if (gid < Nq * LDIM) {
        const int q = gid >> 6, l = gid & 63;
        float a = pos_query[q*3+0] * (W1[0*LDIM+l] + W1[6*LDIM+l]);
        a = fmaf(pos_query[q*3+1], W1[1*LDIM+l] + W1[7*LDIM+l], a);
        a = fmaf(pos_query[q*3+2], W1[2*LDIM+l] + W1[8*LDIM+l], a);
        A[gid] = a;
    }
    if (gid < LDIM) w2s[gid] = W2[gid] * LOG2E;
    // P4[o]
    if (gid < NoA) {
        float4 pp = make_float4(0.f, 0.f, 0.f, 0.f);
        if (gid < No)
            pp = make_float4(pos_obs[gid*3+0], pos_obs[gid*3+1], pos_obs[gid*3+2],
                             obs_mask[gid] ? (float)(obs_batch[gid] + 1) : 0.0f);
        P4[gid] = pp;
    }
    // qrange[q]
    if (gid < Nq) {
        const int b = query_batch[gid];
        int lo = 0, hi = No;
        while (lo < hi) { int mid = (lo + hi) >> 1; if (obs_batch[mid] < b) lo = mid + 1; else hi = mid; }
        const int s = lo;
        hi = No;
        while (lo < hi) { int mid = (lo + hi) >> 1; if (obs_batch[mid] < b + 1) lo = mid + 1; else hi = mid; }
        qrange[gid] = make_int2(s, lo);
    }
}

// K2: 32-query tile x 64-obs chunk. Wave = 8 queries x 64 obs.
// Computes masked logits (log2-scaled), then per-(q,chunk) max m_c and sum
// s_c, and stores CHUNK-NORMALIZED e_c = 2^(lg - m_c) (0 for invalid), plus
// (m_c, s_c). pv then needs no per-element exp2 and only scans nc partials.
__global__ __launch_bounds__(256) void gano_logits(
    const float4* __restrict__ Bi, const float4* __restrict__ P4,
    const float* __restrict__ A, const float* __restrict__ w2s,
    const float* __restrict__ pos_query,
    const int* __restrict__ obs_batch, const int* __restrict__ query_batch,
    float* __restrict__ ec, float* __restrict__ cmax, float* __restrict__ csum,
    int No, int NoA, int nC)
{
    const int c  = blockIdx.x;
    const int q0 = blockIdx.y * QT2;
    if ((c << 6) >= No) return;
    // batch-span intersection early-exit (both arrays sorted)
    const int c_lo = obs_batch[c << 6];
    const int c_hi = obs_batch[min((c << 6) + 63, No - 1)];
    if (c_lo > query_batch[q0 + QT2 - 1] || c_hi < query_batch[q0]) return;

    __shared__ float4 a4[QT2][16];
    __shared__ float4 w2_4[16];
    __shared__ float4 qp4[QT2];

    const int tid = threadIdx.x;
    for (int i = tid; i < QT2 * 16; i += 256)
        a4[i >> 4][i & 15] = ((const float4*)A)[((size_t)(q0 + (i >> 4)) << 4) + (i & 15)];
    if (tid < 16) w2_4[tid] = ((const float4*)w2s)[tid];
    if (tid < QT2) {
        const int q = q0 + tid;
        qp4[tid] = make_float4(pos_query[q*3+0], pos_query[q*3+1], pos_query[q*3+2],
                               (float)(query_batch[q] + 1));
    }
    __syncthreads();

    const int lane = tid & 63, wid = tid >> 6;
    const float4 p = P4[(c << 6) + lane];
    const float4* Bc = Bi + ((size_t)c << 10) + lane;

    float lgq[QW];
    #pragma unroll
    for (int j = 0; j < QW; ++j) lgq[j] = 0.0f;

    #pragma unroll
    for (int g = 0; g < 16; ++g) {
        const float4 Bv = Bc[g << 6];
        const float4 w  = w2_4[g];
        #pragma unroll
        for (int j = 0; j < QW; ++j) {
            const float4 a = a4[wid * QW + j][g];
            lgq[j] = fmaf(fmaxf(a.x + Bv.x, 0.f), w.x, lgq[j]);
            lgq[j] = fmaf(fmaxf(a.y + Bv.y, 0.f), w.y, lgq[j]);
            lgq[j] = fmaf(fmaxf(a.z + Bv.z, 0.f), w.z, lgq[j]);
            lgq[j] = fmaf(fmaxf(a.w + Bv.w, 0.f), w.w, lgq[j]);
        }
    }

    // mask
    #pragma unroll
    for (int j = 0; j < QW; ++j) {
        const float4 qp = qp4[wid * QW + j];
        const float dx = qp.x - p.x, dy = qp.y - p.y, dz = qp.z - p.z;
        const float d2 = fmaf(dz, dz, fmaf(dy, dy, dx * dx));
        const bool valid = (p.w == qp.w) & (d2 <= 1.0f);
        lgq[j] = valid ? lgq[j] : -INFINITY;
    }

    // per-query chunk reduce (8 independent chains, ILP-interleaved)
    float mc[QW];
    #pragma unroll
    for (int j = 0; j < QW; ++j) mc[j] = lgq[j];
    #pragma unroll
    for (int msk = 32; msk; msk >>= 1) {
        #pragma unroll
        for (int j = 0; j < QW; ++j) mc[j] = fmaxf(mc[j], __shfl_xor(mc[j], msk, 64));
    }
    float ev[QW], sc[QW];
    #pragma unroll
    for (int j = 0; j < QW; ++j) {
        ev[j] = (mc[j] == -INFINITY) ? 0.0f : fast_exp2(lgq[j] - mc[j]);
        sc[j] = ev[j];
    }
    #pragma unroll
    for (int msk = 32; msk; msk >>= 1) {
        #pragma unroll
        for (int j = 0; j < QW; ++j) sc[j] += __shfl_xor(sc[j], msk, 64);
    }

    float* erow = ec + (size_t)(q0 + wid * QW) * NoA + (c << 6) + lane;
    #pragma unroll
    for (int j = 0; j < QW; ++j) erow[(size_t)j * NoA] = ev[j];
    if (lane == 0) {
        #pragma unroll
        for (int j = 0; j < QW; ++j) {
            const int q = q0 + wid * QW + j;
            cmax[(size_t)q * nC + c] = mc[j];
            csum[(size_t)q * nC + c] = sc[j];
        }
    }
}

// K3: 4 queries per block, 4 waves. Phase 1: wave wid -> query q0+wid,
// scan nc chunk partials (m_c, s_c) -> M, D, per-chunk scales in LDS.
// Phase 2: chunks strided across waves; inner loop = pure load+fma
// (e_c from LDS b128 broadcast, V coalesced). Writes d_out directly.
__global__ __launch_bounds__(256) void gano_pv(
    const float* __restrict__ ec, const float* __restrict__ V,
    const float* __restrict__ cmax, const float* __restrict__ csum,
    const int2* __restrict__ qrange,
    float* __restrict__ out, int NoA, int nC)
{
    const int q0  = blockIdx.x * QT3;
    const int tid = threadIdx.x, lane = tid & 63, wid = tid >> 6;

    __shared__ float sD[QT3];
    __shared__ float sScale[QT3][64];   // per-chunk scale, index c-c0
    __shared__ float4 e4[4][LDIM];
    __shared__ float sacc[4][QT3][LDIM];

    const int s4  = qrange[q0].x;
    const int e4u = qrange[q0 + QT3 - 1].y;
    const int c0  = s4 >> 6;
    const int c1  = (e4u > s4) ? ((e4u - 1) >> 6) : (c0 - 1);
    const int nc  = c1 - c0 + 1;   // <= nC (32 here), fits one lane pass

    // phase 1: wave `wid` -> query q0+wid
    {
        const int q = q0 + wid;
        const bool on = (lane < nc);
        const float mcv = on ? cmax[(size_t)q * nC + c0 + lane] : -INFINITY;
        const float scv = on ? csum[(size_t)q * nC + c0 + lane] : 0.0f;
        float mx = mcv;
        #pragma unroll
        for (int m = 32; m; m >>= 1) mx = fmaxf(mx, __shfl_xor(mx, m, 64));
        const float Mq = (mx == -INFINITY) ? 0.0f : mx;
        const float scale = (mcv == -INFINITY) ? 0.0f : fast_exp2(mcv - Mq);
        float d = scv * scale;
        #pragma unroll
        for (int m = 32; m; m >>= 1) d += __shfl_xor(d, m, 64);
        if (on) sScale[wid][lane] = scale;
        if (lane == 0) sD[wid] = d;
    }
    __syncthreads();

    float acc0 = 0.f, acc1 = 0.f, acc2 = 0.f, acc3 = 0.f;

    if (nc > 0) {
        const float* r0 = ec + (size_t)(q0 + 0) * NoA;
        const float* r1 = ec + (size_t)(q0 + 1) * NoA;
        const float* r2 = ec + (size_t)(q0 + 2) * NoA;
        const float* r3 = ec + (size_t)(q0 + 3) * NoA;
        for (int c = c0 + wid; c <= c1; c += 4) {
            const int o = (c << 6) + lane;
            const int ci = c - c0;
            float4 evv;
            evv.x = r0[o] * sScale[0][ci];
            evv.y = r1[o] * sScale[1][ci];
            evv.z = r2[o] * sScale[2][ci];
            evv.w = r3[o] * sScale[3][ci];
            e4[wid][lane] = evv;
            const float* Vc = V + ((size_t)c << 12) + lane;
            #pragma unroll
            for (int oo = 0; oo < LDIM; ++oo) {
                const float4 e = e4[wid][oo];   // b128 broadcast (wave-private)
                const float vv = Vc[oo << 6];   // coalesced 256B line
                acc0 = fmaf(e.x, vv, acc0);
                acc1 = fmaf(e.y, vv, acc1);
                acc2 = fmaf(e.z, vv, acc2);
                acc3 = fmaf(e.w, vv, acc3);
            }
        }
    }

    sacc[wid][0][lane] = acc0;
    sacc[wid][1][lane] = acc1;
    sacc[wid][2][lane] = acc2;
    sacc[wid][3][lane] = acc3;
    __syncthreads();

    {
        const int q = wid;
        const float a = (sacc[0][q][lane] + sacc[1][q][lane]) +
                        (sacc[2][q][lane] + sacc[3][q][lane]);
        out[(size_t)(q0 + q) * LDIM + lane] = a / fmaxf(sD[q], 1e-30f);
    }
}

extern "C" void kernel_launch(void* const* d_in, const int* in_sizes, int n_in,
                              void* d_out, int out_size, void* d_ws, size_t ws_size,
                              hipStream_t stream) {
    const float* h_obs     = (const float*)d_in[0];
    const float* pos_obs   = (const float*)d_in[1];
    const float* pos_query = (const float*)d_in[2];
    const float* W1        = (const float*)d_in[3];
    const float* b1        = (const float*)d_in[4];
    const float* W2        = (const float*)d_in[5];
    // d_in[6] = b2: constant shift, cancels in softmax -> unused
    const float* Wv        = (const float*)d_in[7];
    const float* bv        = (const float*)d_in[8];
    const int* obs_mask    = (const int*)d_in[9];
    const int* obs_batch   = (const int*)d_in[10];
    const int* query_batch = (const int*)d_in[11];

    const int No  = in_sizes[1] / 3;
    const int Nq  = in_sizes[2] / 3;
    const int NoA = (No + 63) & ~63;
    const int nC  = NoA / 64;

    // ws layout (~10 MB for Nq=1024, No=2048)
    float4* Bi   = (float4*)d_ws;                       // NoA*16 float4
    float4* P4   = Bi + (size_t)NoA * 16;               // NoA float4
    float*  V    = (float*)(P4 + NoA);                  // NoA*64 f
    float*  A    = V + (size_t)NoA * LDIM;              // Nq*64 f
    float*  w2s  = A + (size_t)Nq * LDIM;               // 64 f
    int2*   qr   = (int2*)(w2s + LDIM);                 // Nq int2
    float*  ecb  = (float*)(qr + Nq);                   // Nq*NoA f
    float*  cmax = ecb + (size_t)Nq * NoA;              // Nq*nC f
    float*  csum = cmax + (size_t)Nq * nC;              // Nq*nC f

    gano_pre<<<(NoA * LDIM + 255) / 256, 256, 0, stream>>>(
        h_obs, pos_obs, pos_query, W1, b1, W2, Wv, bv,
        obs_mask, obs_batch, query_batch,
        Bi, P4, V, A, w2s, qr, No, NoA, Nq);

    dim3 g2(nC, Nq / QT2);
    gano_logits<<<g2, 256, 0, stream>>>(Bi, P4, A, w2s, pos_query,
                                        obs_batch, query_batch,
                                        ecb, cmax, csum, No, NoA, nC);

    gano_pv<<<Nq / QT3, 256, 0, stream>>>(ecb, V, cmax, csum, qr,
                                          (float*)d_out, NoA, nC);
}